// Round 18
// baseline (464.491 us; speedup 1.0000x reference)
//
#include <hip/hip_runtime.h>

typedef short short8  __attribute__((ext_vector_type(8)));
typedef float f32x4   __attribute__((ext_vector_type(4)));

#define B_TOTAL 4096
#define T_STEPS 512
#define F_IN    32
#define H_DIM   60
#define KW      92      // F + H
#define BC      8       // REAL batch rows per block (2 blocks/CU, anti-phased)
#define BCP     16      // padded rows in tiles/LDS (rows 8-15 = lockstep junk)
#define HPITCH  72      // h-LDS row pitch in halves (144B rows, 2-way-free)

#define MFMA(A, B, C) __builtin_amdgcn_mfma_f32_16x16x32_bf16((A), (B), (C), 0, 0, 0)

__device__ __forceinline__ unsigned short bf16rne(float f) {
    unsigned int u = __float_as_uint(f);
    u += 0x7FFFu + ((u >> 16) & 1u);
    return (unsigned short)(u >> 16);
}
__device__ __forceinline__ float rcpf(float z) {
    return __builtin_amdgcn_rcpf(z);            // v_rcp_f32, 1 ulp
}
__device__ __forceinline__ float exp2f_(float z) {
#if __has_builtin(__builtin_amdgcn_exp2f)
    return __builtin_amdgcn_exp2f(z);           // v_exp_f32
#else
    float r; asm("v_exp_f32 %0, %1" : "=v"(r) : "v"(z)); return r;
#endif
}

// LDS-visibility barrier WITHOUT the vmcnt(0) drain __syncthreads() imposes:
// outstanding global loads (x prefetch) stay in flight across it.
#define BAR()                                                                   \
    {                                                                           \
        asm volatile("s_waitcnt lgkmcnt(0)" ::: "memory");                      \
        __builtin_amdgcn_sched_barrier(0);                                      \
        __builtin_amdgcn_s_barrier();                                           \
        __builtin_amdgcn_sched_barrier(0);                                      \
    }

// float4 pair -> packed bf16 short8 fragment, RNE, via v_cvt_pk_bf16_f32
#define CVTH(VA, VB, OH)                                                        \
    {                                                                           \
        int4 hp;                                                                \
        asm("v_cvt_pk_bf16_f32 %0, %1, %2" : "=v"(hp.x) : "v"((VA).x), "v"((VA).y)); \
        asm("v_cvt_pk_bf16_f32 %0, %1, %2" : "=v"(hp.y) : "v"((VA).z), "v"((VA).w)); \
        asm("v_cvt_pk_bf16_f32 %0, %1, %2" : "=v"(hp.z) : "v"((VB).x), "v"((VB).y)); \
        asm("v_cvt_pk_bf16_f32 %0, %1, %2" : "=v"(hp.w) : "v"((VB).z), "v"((VB).w)); \
        OH = __builtin_bit_cast(short8, hp);                                    \
    }

// Paired LSTM cell update for units u0 (gates P) and u1 (gates Q).
// Pre-activations pre-scaled: i,f,o by log2e; j by 2*log2e; forget +1 folded.
// D1/D2 reciprocals merged across the pair (products bounded); D3 per-unit.
#define CELL2(P, Q, H0, H1)                                                     \
    float h0, h1;                                                               \
    {                                                                           \
        float ei0 = exp2f_(-P[0]), ei1 = exp2f_(-Q[0]);                         \
        float qj0 = exp2f_(P[1]),  qj1 = exp2f_(Q[1]);                          \
        float ef0 = exp2f_(-P[2]), ef1 = exp2f_(-Q[2]);                         \
        float D10 = (1.0f + ei0) * (qj0 + 1.0f);                                \
        float D11 = (1.0f + ei1) * (qj1 + 1.0f);                                \
        float r1  = rcpf(D10 * D11);                                            \
        float D20 = 1.0f + ef0, D21 = 1.0f + ef1;                               \
        float r2  = rcpf(D20 * D21);                                            \
        cst0 = cst0 * (D21 * r2) + (qj0 - 1.0f) * (D11 * r1);                   \
        cst1 = cst1 * (D20 * r2) + (qj1 - 1.0f) * (D10 * r1);                   \
        float zc0 = __builtin_amdgcn_fmed3f(cst0 * (2.0f * 1.44269504088896340736f), -126.0f, 126.0f); \
        float zc1 = __builtin_amdgcn_fmed3f(cst1 * (2.0f * 1.44269504088896340736f), -126.0f, 126.0f); \
        float qc0 = exp2f_(zc0), qc1 = exp2f_(zc1);                             \
        float eo0 = exp2f_(-P[3]), eo1 = exp2f_(-Q[3]);                         \
        H0 = (qc0 - 1.0f) * rcpf((qc0 + 1.0f) * (1.0f + eo0));                  \
        H1 = (qc1 - 1.0f) * rcpf((qc1 + 1.0f) * (1.0f + eo1));                  \
    }

__global__ __launch_bounds__(512, 4)
void lstm_mfma_kernel(const float* __restrict__ x,
                      const float* __restrict__ wk,
                      const float* __restrict__ bias,
                      const float* __restrict__ dense_w,
                      const float* __restrict__ dense_b,
                      float* __restrict__ out)
{
    // Double-buffered h-state, bf16, PAIR-PERMUTED columns: h of units
    // (8w+kg, 8w+4+kg) lives at cols (2m, 2m+1), m = 4w+kg. Weights' K-order
    // is gathered with the same permutation, so MFMA semantics are unchanged.
    // Rows 8..15 carry lockstep junk (pad batch rows) — column-local in MFMA.
    __shared__ __align__(16) short Hhi[2][BCP][HPITCH];
    __shared__ float Hf[BCP][64];           // final-step h, f32, old unit order

    const int tid  = threadIdx.x;
    const int lane = tid & 63;
    const int w    = tid >> 6;              // wave 0..7
    const int b0   = blockIdx.x * BC;
    const int lm   = lane & 15;             // batch row (B-operand N index)
    const int kg   = lane >> 4;             // K octet group 0..3
    const int lk8  = kg * 8;

    const float LOG2E = 1.44269504088896340736f;

    // ---------------- A fragments = W^T (static), exp2-prescaled, bf16 ------
    short8 wh[2][3];
    f32x4  biasv[2];
    #pragma unroll
    for (int tt = 0; tt < 2; ++tt) {
        const int mt = 2 * w + tt;
        if (mt < 15) {
            const int uo = 4 * mt + kg;
            f32x4 bv;
            #pragma unroll
            for (int r = 0; r < 4; ++r) {
                const float sc = (r == 1) ? 2.0f * LOG2E : LOG2E;
                bv[r] = (bias[r * 60 + uo] + (r == 2 ? 1.0f : 0.0f)) * sc;
            }
            biasv[tt] = bv;
            const int c = 16 * mt + lm;          // A-operand M-row
            const int u = c >> 2, g = c & 3;
            const float gsc = (g == 1) ? 2.0f * LOG2E : LOG2E;
            // s = 0: x K-step, direct k order
            {
                short8 hv;
                #pragma unroll
                for (int e = 0; e < 8; ++e)
                    hv[e] = (short)bf16rne(wk[(lk8 + e) * 240 + g * 60 + u] * gsc);
                wh[tt][0] = hv;
            }
            // s = 1,2: h K-steps, pair-permuted column order
            #pragma unroll
            for (int s = 1; s < 3; ++s) {
                short8 hv;
                #pragma unroll
                for (int e = 0; e < 8; ++e) {
                    const int cc = (s - 1) * 32 + lk8 + e;   // permuted col
                    const int m  = cc >> 1, bit = cc & 1;
                    const int uk = 8 * (m >> 2) + 4 * bit + (m & 3);
                    float wv = (uk < H_DIM) ? wk[(F_IN + uk) * 240 + g * 60 + u] * gsc : 0.0f;
                    hv[e] = (short)bf16rne(wv);
                }
                wh[tt][s] = hv;
            }
        } else {
            biasv[tt] = (f32x4){0.f, 0.f, 0.f, 0.f};
            #pragma unroll
            for (int s = 0; s < 3; ++s) wh[tt][s] = (short8)0;
        }
    }
    const int u0 = 8 * w + kg;              // unit of tile mt0 output (old order)
    const int u1 = 8 * w + 4 + kg;          // unit of tile mt1 output
    const int mIdx = 4 * w + kg;            // packed-pair column index
    const bool t1ok = (2 * w + 1 < 15);

    // ---------------- zero h buffers (h0 = 0, pad cols = 0) -----------------
    for (int i = tid; i < 2 * BCP * HPITCH; i += 512)
        (&Hhi[0][0][0])[i] = 0;

    // ---------------- x fragments: lane owns (row lm&7, k lk8..lk8+7) -------
    // Rows 8..15 alias rows 0..7 (duplicate loads, L1-hit; junk stays in
    // its own output column). Real rows: b0..b0+7 — never OOB.
    const float* xrow = x + (size_t)(b0 + (lm & 7)) * (T_STEPS * F_IN) + lk8;
    float4 va0 = *reinterpret_cast<const float4*>(xrow);
    float4 vb0 = *reinterpret_cast<const float4*>(xrow + 4);
    short8 axh;
    CVTH(va0, vb0, axh)
    // prefetch slot B <- x(1); slot A filled in-loop with x(t+2)
    float4 sBa = *reinterpret_cast<const float4*>(xrow + 1 * F_IN);
    float4 sBb = *reinterpret_cast<const float4*>(xrow + 1 * F_IN + 4);
    float4 sAa, sAb;
    const float* xp2 = xrow + 2 * F_IN;     // bumped by 2*F_IN per step-pair

    float cst0 = 0.f, cst1 = 0.f;           // cell state for (b=lm, u0/u1)
    __syncthreads();

// One LSTM step. 3-deep bf16 MFMA chains (2 independent), setprio(1) around
// the MFMA cluster to de-phase waves. Raw barrier: lgkm only; the 2
// outstanding x prefetch loads stay in flight across it. h pair = one b32.
#define STEPX(CUR, NXT, DOLOAD, LA, LB, XOFF, DOCVT, CA, CB, LASTF)             \
    {                                                                           \
        short8 uh1 = *reinterpret_cast<const short8*>(&Hhi[CUR][lm][lk8]);      \
        short8 uh2 = *reinterpret_cast<const short8*>(&Hhi[CUR][lm][32 + lk8]); \
        if (DOLOAD) {                                                           \
            LA = *reinterpret_cast<const float4*>(xp2 + (XOFF));                \
            LB = *reinterpret_cast<const float4*>(xp2 + (XOFF) + 4);            \
        }                                                                       \
        __builtin_amdgcn_s_setprio(1);                                          \
        f32x4 p = MFMA(wh[0][0], axh, biasv[0]);                                \
        f32x4 q = MFMA(wh[1][0], axh, biasv[1]);                                \
        p = MFMA(wh[0][1], uh1, p);                                             \
        q = MFMA(wh[1][1], uh1, q);                                             \
        p = MFMA(wh[0][2], uh2, p);                                             \
        q = MFMA(wh[1][2], uh2, q);                                             \
        __builtin_amdgcn_s_setprio(0);                                          \
        CELL2(p, q, h0, h1)                                                     \
        int pk;                                                                 \
        asm("v_cvt_pk_bf16_f32 %0, %1, %2" : "=v"(pk) : "v"(h0), "v"(h1));      \
        if (LASTF) {                                                            \
            Hf[lm][u0] = h0;                                                    \
            if (t1ok) Hf[lm][u1] = h1;                                          \
        } else {                                                                \
            *reinterpret_cast<int*>(&Hhi[NXT][lm][2 * mIdx]) = pk;              \
        }                                                                       \
        if (DOCVT) CVTH(CA, CB, axh)                                            \
        BAR()                                                                   \
    }

    for (int t = 0; t < T_STEPS - 2; t += 2) {
        STEPX(0, 1, 1, sAa, sAb, 0,    1, sBa, sBb, 0)  // load x(t+2)->A, cvt x(t+1)<-B
        STEPX(1, 0, 1, sBa, sBb, F_IN, 1, sAa, sAb, 0)  // load x(t+3)->B, cvt x(t+2)<-A
        xp2 += 2 * F_IN;
    }
    // tail: t = 510 (no load; cvt x(511) from B), t = 511 (LAST -> Hf)
    STEPX(0, 1, 0, sAa, sAb, 0, 1, sBa, sBb, 0)
    STEPX(1, 0, 0, sAa, sAb, 0, 0, sBa, sBb, 1)

    // ---------------- epilogue: out[b] = h . dense_w + dense_b --------------
    if (tid < BC) {
        float acc = dense_b[0];
        #pragma unroll 4
        for (int uu = 0; uu < H_DIM; ++uu)
            acc = fmaf(Hf[tid][uu], dense_w[uu], acc);
        out[b0 + tid] = acc;
    }
}

extern "C" void kernel_launch(void* const* d_in, const int* in_sizes, int n_in,
                              void* d_out, int out_size, void* d_ws, size_t ws_size,
                              hipStream_t stream) {
    const float* x       = (const float*)d_in[0];
    const float* wk      = (const float*)d_in[1];
    const float* bias    = (const float*)d_in[2];
    const float* dense_w = (const float*)d_in[3];
    const float* dense_b = (const float*)d_in[4];
    float* out = (float*)d_out;

    lstm_mfma_kernel<<<B_TOTAL / BC, 512, 0, stream>>>(
        x, wk, bias, dense_w, dense_b, out);
}

// Round 19
// 463.435 us; speedup vs baseline: 1.0023x; 1.0023x over previous
//
#include <hip/hip_runtime.h>

typedef short short8  __attribute__((ext_vector_type(8)));
typedef float f32x4   __attribute__((ext_vector_type(4)));

#define B_TOTAL 4096
#define T_STEPS 512
#define F_IN    32
#define H_DIM   60
#define KW      92      // F + H
#define BC      8       // REAL batch rows per block (2 blocks/CU, anti-phased)
#define BCP     16      // padded rows in tiles/LDS (rows 8-15 = lockstep junk)
#define HPITCH  72      // h-LDS row pitch in halves (144B rows, 2-way-free)

#define MFMA(A, B, C) __builtin_amdgcn_mfma_f32_16x16x32_bf16((A), (B), (C), 0, 0, 0)

__device__ __forceinline__ unsigned short bf16rne(float f) {
    unsigned int u = __float_as_uint(f);
    u += 0x7FFFu + ((u >> 16) & 1u);
    return (unsigned short)(u >> 16);
}
__device__ __forceinline__ float rcpf(float z) {
    return __builtin_amdgcn_rcpf(z);            // v_rcp_f32, 1 ulp
}
__device__ __forceinline__ float exp2f_(float z) {
#if __has_builtin(__builtin_amdgcn_exp2f)
    return __builtin_amdgcn_exp2f(z);           // v_exp_f32
#else
    float r; asm("v_exp_f32 %0, %1" : "=v"(r) : "v"(z)); return r;
#endif
}

// LDS-visibility barrier WITHOUT the vmcnt(0) drain __syncthreads() imposes:
// outstanding global loads (x prefetch) stay in flight across it.
#define BAR()                                                                   \
    {                                                                           \
        asm volatile("s_waitcnt lgkmcnt(0)" ::: "memory");                      \
        __builtin_amdgcn_sched_barrier(0);                                      \
        __builtin_amdgcn_s_barrier();                                           \
        __builtin_amdgcn_sched_barrier(0);                                      \
    }

// float4 pair -> packed bf16 short8 fragment, RNE, via v_cvt_pk_bf16_f32
#define CVTH(VA, VB, OH)                                                        \
    {                                                                           \
        int4 hp;                                                                \
        asm("v_cvt_pk_bf16_f32 %0, %1, %2" : "=v"(hp.x) : "v"((VA).x), "v"((VA).y)); \
        asm("v_cvt_pk_bf16_f32 %0, %1, %2" : "=v"(hp.y) : "v"((VA).z), "v"((VA).w)); \
        asm("v_cvt_pk_bf16_f32 %0, %1, %2" : "=v"(hp.z) : "v"((VB).x), "v"((VB).y)); \
        asm("v_cvt_pk_bf16_f32 %0, %1, %2" : "=v"(hp.w) : "v"((VB).z), "v"((VB).w)); \
        OH = __builtin_bit_cast(short8, hp);                                    \
    }

// Paired LSTM cell update for units u0 (gates P) and u1 (gates Q).
// Pre-activations pre-scaled: i,f,o by log2e; j by 2*log2e; forget +1 folded.
// D1/D2 reciprocals merged across the pair (products bounded); D3 per-unit.
#define CELL2(P, Q, H0, H1)                                                     \
    float h0, h1;                                                               \
    {                                                                           \
        float ei0 = exp2f_(-P[0]), ei1 = exp2f_(-Q[0]);                         \
        float qj0 = exp2f_(P[1]),  qj1 = exp2f_(Q[1]);                          \
        float ef0 = exp2f_(-P[2]), ef1 = exp2f_(-Q[2]);                         \
        float D10 = (1.0f + ei0) * (qj0 + 1.0f);                                \
        float D11 = (1.0f + ei1) * (qj1 + 1.0f);                                \
        float r1  = rcpf(D10 * D11);                                            \
        float D20 = 1.0f + ef0, D21 = 1.0f + ef1;                               \
        float r2  = rcpf(D20 * D21);                                            \
        cst0 = cst0 * (D21 * r2) + (qj0 - 1.0f) * (D11 * r1);                   \
        cst1 = cst1 * (D20 * r2) + (qj1 - 1.0f) * (D10 * r1);                   \
        float zc0 = __builtin_amdgcn_fmed3f(cst0 * (2.0f * 1.44269504088896340736f), -126.0f, 126.0f); \
        float zc1 = __builtin_amdgcn_fmed3f(cst1 * (2.0f * 1.44269504088896340736f), -126.0f, 126.0f); \
        float qc0 = exp2f_(zc0), qc1 = exp2f_(zc1);                             \
        float eo0 = exp2f_(-P[3]), eo1 = exp2f_(-Q[3]);                         \
        H0 = (qc0 - 1.0f) * rcpf((qc0 + 1.0f) * (1.0f + eo0));                  \
        H1 = (qc1 - 1.0f) * rcpf((qc1 + 1.0f) * (1.0f + eo1));                  \
    }

__global__ __launch_bounds__(512, 4)
void lstm_mfma_kernel(const float* __restrict__ x,
                      const float* __restrict__ wk,
                      const float* __restrict__ bias,
                      const float* __restrict__ dense_w,
                      const float* __restrict__ dense_b,
                      float* __restrict__ out)
{
    // Double-buffered h-state, bf16, PAIR-PERMUTED columns: h of units
    // (8w+kg, 8w+4+kg) lives at cols (2m, 2m+1), m = 4w+kg. Weights' K-order
    // is gathered with the same permutation, so MFMA semantics are unchanged.
    // Rows 8..15 carry lockstep junk (pad batch rows) — column-local in MFMA.
    __shared__ __align__(16) short Hhi[2][BCP][HPITCH];
    __shared__ float Hf[BCP][64];           // final-step h, f32, old unit order

    const int tid  = threadIdx.x;
    const int lane = tid & 63;
    const int w    = tid >> 6;              // wave 0..7
    const int b0   = blockIdx.x * BC;
    const int lm   = lane & 15;             // batch row (B-operand N index)
    const int kg   = lane >> 4;             // K octet group 0..3
    const int lk8  = kg * 8;

    const float LOG2E = 1.44269504088896340736f;

    // ---------------- A fragments = W^T (static), exp2-prescaled, bf16 ------
    short8 wh[2][3];
    f32x4  biasv[2];
    #pragma unroll
    for (int tt = 0; tt < 2; ++tt) {
        const int mt = 2 * w + tt;
        if (mt < 15) {
            const int uo = 4 * mt + kg;
            f32x4 bv;
            #pragma unroll
            for (int r = 0; r < 4; ++r) {
                const float sc = (r == 1) ? 2.0f * LOG2E : LOG2E;
                bv[r] = (bias[r * 60 + uo] + (r == 2 ? 1.0f : 0.0f)) * sc;
            }
            biasv[tt] = bv;
            const int c = 16 * mt + lm;          // A-operand M-row
            const int u = c >> 2, g = c & 3;
            const float gsc = (g == 1) ? 2.0f * LOG2E : LOG2E;
            // s = 0: x K-step, direct k order
            {
                short8 hv;
                #pragma unroll
                for (int e = 0; e < 8; ++e)
                    hv[e] = (short)bf16rne(wk[(lk8 + e) * 240 + g * 60 + u] * gsc);
                wh[tt][0] = hv;
            }
            // s = 1,2: h K-steps, pair-permuted column order
            #pragma unroll
            for (int s = 1; s < 3; ++s) {
                short8 hv;
                #pragma unroll
                for (int e = 0; e < 8; ++e) {
                    const int cc = (s - 1) * 32 + lk8 + e;   // permuted col
                    const int m  = cc >> 1, bit = cc & 1;
                    const int uk = 8 * (m >> 2) + 4 * bit + (m & 3);
                    float wv = (uk < H_DIM) ? wk[(F_IN + uk) * 240 + g * 60 + u] * gsc : 0.0f;
                    hv[e] = (short)bf16rne(wv);
                }
                wh[tt][s] = hv;
            }
        } else {
            biasv[tt] = (f32x4){0.f, 0.f, 0.f, 0.f};
            #pragma unroll
            for (int s = 0; s < 3; ++s) wh[tt][s] = (short8)0;
        }
    }
    const int u0 = 8 * w + kg;              // unit of tile mt0 output (old order)
    const int u1 = 8 * w + 4 + kg;          // unit of tile mt1 output
    const int mIdx = 4 * w + kg;            // packed-pair column index
    const bool t1ok = (2 * w + 1 < 15);

    // ---------------- zero h buffers (h0 = 0, pad cols = 0) -----------------
    for (int i = tid; i < 2 * BCP * HPITCH; i += 512)
        (&Hhi[0][0][0])[i] = 0;

    // ---------------- x fragments: lane owns (row lm&7, k lk8..lk8+7) -------
    // Rows 8..15 alias rows 0..7 (duplicate loads, L1-hit; junk stays in
    // its own output column). Real rows: b0..b0+7 — never OOB.
    const float* xrow = x + (size_t)(b0 + (lm & 7)) * (T_STEPS * F_IN) + lk8;
    float4 va0 = *reinterpret_cast<const float4*>(xrow);
    float4 vb0 = *reinterpret_cast<const float4*>(xrow + 4);
    short8 axh;
    CVTH(va0, vb0, axh)
    // prefetch slot B <- x(1); slot A filled in-loop with x(t+2)
    float4 sBa = *reinterpret_cast<const float4*>(xrow + 1 * F_IN);
    float4 sBb = *reinterpret_cast<const float4*>(xrow + 1 * F_IN + 4);
    float4 sAa, sAb;
    const float* xp2 = xrow + 2 * F_IN;     // bumped by 2*F_IN per step-pair

    float cst0 = 0.f, cst1 = 0.f;           // cell state for (b=lm, u0/u1)
    __syncthreads();

// One LSTM step. 3-deep bf16 MFMA chains (2 independent). NO setprio: with
// 4 waves/SIMD from 2 independent blocks, prio-1 MFMA windows starve the
// prio-0 CELL phase (R18's 2x serialization); natural inter-block anti-phase
// replaces the manufactured de-phasing. Raw barrier: lgkm only; the 2
// outstanding x prefetch loads stay in flight across it. h pair = one b32.
#define STEPX(CUR, NXT, DOLOAD, LA, LB, XOFF, DOCVT, CA, CB, LASTF)             \
    {                                                                           \
        short8 uh1 = *reinterpret_cast<const short8*>(&Hhi[CUR][lm][lk8]);      \
        short8 uh2 = *reinterpret_cast<const short8*>(&Hhi[CUR][lm][32 + lk8]); \
        if (DOLOAD) {                                                           \
            LA = *reinterpret_cast<const float4*>(xp2 + (XOFF));                \
            LB = *reinterpret_cast<const float4*>(xp2 + (XOFF) + 4);            \
        }                                                                       \
        f32x4 p = MFMA(wh[0][0], axh, biasv[0]);                                \
        f32x4 q = MFMA(wh[1][0], axh, biasv[1]);                                \
        p = MFMA(wh[0][1], uh1, p);                                             \
        q = MFMA(wh[1][1], uh1, q);                                             \
        p = MFMA(wh[0][2], uh2, p);                                             \
        q = MFMA(wh[1][2], uh2, q);                                             \
        CELL2(p, q, h0, h1)                                                     \
        int pk;                                                                 \
        asm("v_cvt_pk_bf16_f32 %0, %1, %2" : "=v"(pk) : "v"(h0), "v"(h1));      \
        if (LASTF) {                                                            \
            Hf[lm][u0] = h0;                                                    \
            if (t1ok) Hf[lm][u1] = h1;                                          \
        } else {                                                                \
            *reinterpret_cast<int*>(&Hhi[NXT][lm][2 * mIdx]) = pk;              \
        }                                                                       \
        if (DOCVT) CVTH(CA, CB, axh)                                            \
        BAR()                                                                   \
    }

    for (int t = 0; t < T_STEPS - 2; t += 2) {
        STEPX(0, 1, 1, sAa, sAb, 0,    1, sBa, sBb, 0)  // load x(t+2)->A, cvt x(t+1)<-B
        STEPX(1, 0, 1, sBa, sBb, F_IN, 1, sAa, sAb, 0)  // load x(t+3)->B, cvt x(t+2)<-A
        xp2 += 2 * F_IN;
    }
    // tail: t = 510 (no load; cvt x(511) from B), t = 511 (LAST -> Hf)
    STEPX(0, 1, 0, sAa, sAb, 0, 1, sBa, sBb, 0)
    STEPX(1, 0, 0, sAa, sAb, 0, 0, sBa, sBb, 1)

    // ---------------- epilogue: out[b] = h . dense_w + dense_b --------------
    if (tid < BC) {
        float acc = dense_b[0];
        #pragma unroll 4
        for (int uu = 0; uu < H_DIM; ++uu)
            acc = fmaf(Hf[tid][uu], dense_w[uu], acc);
        out[b0 + tid] = acc;
    }
}

extern "C" void kernel_launch(void* const* d_in, const int* in_sizes, int n_in,
                              void* d_out, int out_size, void* d_ws, size_t ws_size,
                              hipStream_t stream) {
    const float* x       = (const float*)d_in[0];
    const float* wk      = (const float*)d_in[1];
    const float* bias    = (const float*)d_in[2];
    const float* dense_w = (const float*)d_in[3];
    const float* dense_b = (const float*)d_in[4];
    float* out = (float*)d_out;

    lstm_mfma_kernel<<<B_TOTAL / BC, 512, 0, stream>>>(
        x, wk, bias, dense_w, dense_b, out);
}

// Round 20
// 236.094 us; speedup vs baseline: 1.9674x; 1.9629x over previous
//
#include <hip/hip_runtime.h>

typedef short short8  __attribute__((ext_vector_type(8)));
typedef float f32x4   __attribute__((ext_vector_type(4)));

#define B_TOTAL 4096
#define T_STEPS 512
#define F_IN    32
#define H_DIM   60
#define KW      92      // F + H
#define BC      16      // batch rows per block
#define HPITCH  72      // h-LDS row pitch in halves (144B rows, 2-way-free)

#define MFMA(A, B, C) __builtin_amdgcn_mfma_f32_16x16x32_bf16((A), (B), (C), 0, 0, 0)

__device__ __forceinline__ unsigned short bf16rne(float f) {
    unsigned int u = __float_as_uint(f);
    u += 0x7FFFu + ((u >> 16) & 1u);
    return (unsigned short)(u >> 16);
}
__device__ __forceinline__ float rcpf(float z) {
    return __builtin_amdgcn_rcpf(z);            // v_rcp_f32, 1 ulp
}
__device__ __forceinline__ float exp2f_(float z) {
#if __has_builtin(__builtin_amdgcn_exp2f)
    return __builtin_amdgcn_exp2f(z);           // v_exp_f32
#else
    float r; asm("v_exp_f32 %0, %1" : "=v"(r) : "v"(z)); return r;
#endif
}

// LDS-visibility barrier WITHOUT the vmcnt(0) drain __syncthreads() imposes:
// outstanding global loads (x prefetch) stay in flight across it.
#define BAR()                                                                   \
    {                                                                           \
        asm volatile("s_waitcnt lgkmcnt(0)" ::: "memory");                      \
        __builtin_amdgcn_sched_barrier(0);                                      \
        __builtin_amdgcn_s_barrier();                                           \
        __builtin_amdgcn_sched_barrier(0);                                      \
    }

// float4 pair -> packed bf16 short8 fragment, RNE, via v_cvt_pk_bf16_f32
#define CVTH(VA, VB, OH)                                                        \
    {                                                                           \
        int4 hp;                                                                \
        asm("v_cvt_pk_bf16_f32 %0, %1, %2" : "=v"(hp.x) : "v"((VA).x), "v"((VA).y)); \
        asm("v_cvt_pk_bf16_f32 %0, %1, %2" : "=v"(hp.y) : "v"((VA).z), "v"((VA).w)); \
        asm("v_cvt_pk_bf16_f32 %0, %1, %2" : "=v"(hp.z) : "v"((VB).x), "v"((VB).y)); \
        asm("v_cvt_pk_bf16_f32 %0, %1, %2" : "=v"(hp.w) : "v"((VB).z), "v"((VB).w)); \
        OH = __builtin_bit_cast(short8, hp);                                    \
    }

// Paired LSTM cell update for units u0 (gates P) and u1 (gates Q).
// Pre-activations pre-scaled: i,f,o by log2e; j by 2*log2e; forget +1 folded.
// D1/D2 reciprocals merged across the pair (products bounded); D3 per-unit.
#define CELL2(P, Q, H0, H1)                                                     \
    float h0, h1;                                                               \
    {                                                                           \
        float ei0 = exp2f_(-P[0]), ei1 = exp2f_(-Q[0]);                         \
        float qj0 = exp2f_(P[1]),  qj1 = exp2f_(Q[1]);                          \
        float ef0 = exp2f_(-P[2]), ef1 = exp2f_(-Q[2]);                         \
        float D10 = (1.0f + ei0) * (qj0 + 1.0f);                                \
        float D11 = (1.0f + ei1) * (qj1 + 1.0f);                                \
        float r1  = rcpf(D10 * D11);                                            \
        float D20 = 1.0f + ef0, D21 = 1.0f + ef1;                               \
        float r2  = rcpf(D20 * D21);                                            \
        cst0 = cst0 * (D21 * r2) + (qj0 - 1.0f) * (D11 * r1);                   \
        cst1 = cst1 * (D20 * r2) + (qj1 - 1.0f) * (D10 * r1);                   \
        float zc0 = __builtin_amdgcn_fmed3f(cst0 * (2.0f * 1.44269504088896340736f), -126.0f, 126.0f); \
        float zc1 = __builtin_amdgcn_fmed3f(cst1 * (2.0f * 1.44269504088896340736f), -126.0f, 126.0f); \
        float qc0 = exp2f_(zc0), qc1 = exp2f_(zc1);                             \
        float eo0 = exp2f_(-P[3]), eo1 = exp2f_(-Q[3]);                         \
        H0 = (qc0 - 1.0f) * rcpf((qc0 + 1.0f) * (1.0f + eo0));                  \
        H1 = (qc1 - 1.0f) * rcpf((qc1 + 1.0f) * (1.0f + eo1));                  \
    }

__global__ __launch_bounds__(512, 2)
void lstm_mfma_kernel(const float* __restrict__ x,
                      const float* __restrict__ wk,
                      const float* __restrict__ bias,
                      const float* __restrict__ dense_w,
                      const float* __restrict__ dense_b,
                      float* __restrict__ out)
{
    // Double-buffered h-state, bf16, PAIR-PERMUTED columns: h of units
    // (8w+kg, 8w+4+kg) lives at cols (2m, 2m+1), m = 4w+kg. Weights' K-order
    // is gathered with the same permutation, so MFMA semantics are unchanged.
    __shared__ __align__(16) short Hhi[2][BC][HPITCH];
    __shared__ float Hf[BC][64];            // final-step h, f32, old unit order

    const int tid  = threadIdx.x;
    const int lane = tid & 63;
    const int w    = tid >> 6;              // wave 0..7
    const int b0   = blockIdx.x * BC;
    const int lm   = lane & 15;             // batch row (B-operand N index)
    const int kg   = lane >> 4;             // K octet group 0..3
    const int lk8  = kg * 8;

    const float LOG2E = 1.44269504088896340736f;

    // ---------------- A fragments = W^T (static), exp2-prescaled, bf16 ------
    short8 wh[2][3];
    f32x4  biasv[2];
    #pragma unroll
    for (int tt = 0; tt < 2; ++tt) {
        const int mt = 2 * w + tt;
        if (mt < 15) {
            const int uo = 4 * mt + kg;
            f32x4 bv;
            #pragma unroll
            for (int r = 0; r < 4; ++r) {
                const float sc = (r == 1) ? 2.0f * LOG2E : LOG2E;
                bv[r] = (bias[r * 60 + uo] + (r == 2 ? 1.0f : 0.0f)) * sc;
            }
            biasv[tt] = bv;
            const int c = 16 * mt + lm;          // A-operand M-row
            const int u = c >> 2, g = c & 3;
            const float gsc = (g == 1) ? 2.0f * LOG2E : LOG2E;
            // s = 0: x K-step, direct k order
            {
                short8 hv;
                #pragma unroll
                for (int e = 0; e < 8; ++e)
                    hv[e] = (short)bf16rne(wk[(lk8 + e) * 240 + g * 60 + u] * gsc);
                wh[tt][0] = hv;
            }
            // s = 1,2: h K-steps, pair-permuted column order
            #pragma unroll
            for (int s = 1; s < 3; ++s) {
                short8 hv;
                #pragma unroll
                for (int e = 0; e < 8; ++e) {
                    const int cc = (s - 1) * 32 + lk8 + e;   // permuted col
                    const int m  = cc >> 1, bit = cc & 1;
                    const int uk = 8 * (m >> 2) + 4 * bit + (m & 3);
                    float wv = (uk < H_DIM) ? wk[(F_IN + uk) * 240 + g * 60 + u] * gsc : 0.0f;
                    hv[e] = (short)bf16rne(wv);
                }
                wh[tt][s] = hv;
            }
        } else {
            biasv[tt] = (f32x4){0.f, 0.f, 0.f, 0.f};
            #pragma unroll
            for (int s = 0; s < 3; ++s) wh[tt][s] = (short8)0;
        }
    }
    const int u0 = 8 * w + kg;              // unit of tile mt0 output (old order)
    const int u1 = 8 * w + 4 + kg;          // unit of tile mt1 output
    const int mIdx = 4 * w + kg;            // packed-pair column index
    const bool t1ok = (2 * w + 1 < 15);

    // ---------------- zero h buffers (h0 = 0, pad cols = 0) -----------------
    for (int i = tid; i < 2 * BC * HPITCH; i += 512)
        (&Hhi[0][0][0])[i] = 0;

    // ---------------- x fragments: lane owns (row lm, k lk8..lk8+7) ---------
    const float* xrow = x + (size_t)(b0 + lm) * (T_STEPS * F_IN) + lk8;
    // slot A <- x(0), slot B <- x(1); conversion happens post-barrier in-step
    float4 sAa = *reinterpret_cast<const float4*>(xrow);
    float4 sAb = *reinterpret_cast<const float4*>(xrow + 4);
    float4 sBa = *reinterpret_cast<const float4*>(xrow + 1 * F_IN);
    float4 sBb = *reinterpret_cast<const float4*>(xrow + 1 * F_IN + 4);
    short8 axh;
    const float* xp2 = xrow + 2 * F_IN;     // bumped by 2*F_IN per step-pair

    float cst0 = 0.f, cst1 = 0.f;           // cell state for (b=lm, u0/u1)
    __syncthreads();                        // (drains vmcnt: x0/x1 landed)

// One LSTM step. CVTH moved POST-barrier: the 4 cvt_pk are LDS-independent
// work that covers ds_read latency (with the 2 x-MFMAs), and no longer delay
// barrier arrival. Slot SA/SB holds x(t); after converting, the same slot is
// reloaded with x(t+2) (stays in flight across 2 raw barriers). setprio(1)
// de-phases the 2 waves/SIMD (R17-proven). Raw barrier: lgkm only.
#define STEPX(CUR, NXT, DOLOAD, SA, SB, XOFF, LASTF)                            \
    {                                                                           \
        short8 uh1 = *reinterpret_cast<const short8*>(&Hhi[CUR][lm][lk8]);      \
        short8 uh2 = *reinterpret_cast<const short8*>(&Hhi[CUR][lm][32 + lk8]); \
        CVTH(SA, SB, axh)                                                       \
        if (DOLOAD) {                                                           \
            SA = *reinterpret_cast<const float4*>(xp2 + (XOFF));                \
            SB = *reinterpret_cast<const float4*>(xp2 + (XOFF) + 4);            \
        }                                                                       \
        __builtin_amdgcn_s_setprio(1);                                          \
        f32x4 p = MFMA(wh[0][0], axh, biasv[0]);                                \
        f32x4 q = MFMA(wh[1][0], axh, biasv[1]);                                \
        p = MFMA(wh[0][1], uh1, p);                                             \
        q = MFMA(wh[1][1], uh1, q);                                             \
        p = MFMA(wh[0][2], uh2, p);                                             \
        q = MFMA(wh[1][2], uh2, q);                                             \
        __builtin_amdgcn_s_setprio(0);                                          \
        CELL2(p, q, h0, h1)                                                     \
        int pk;                                                                 \
        asm("v_cvt_pk_bf16_f32 %0, %1, %2" : "=v"(pk) : "v"(h0), "v"(h1));      \
        if (LASTF) {                                                            \
            Hf[lm][u0] = h0;                                                    \
            if (t1ok) Hf[lm][u1] = h1;                                          \
        } else {                                                                \
            *reinterpret_cast<int*>(&Hhi[NXT][lm][2 * mIdx]) = pk;              \
        }                                                                       \
        BAR()                                                                   \
    }

    for (int t = 0; t < T_STEPS - 2; t += 2) {
        STEPX(0, 1, 1, sAa, sAb, 0,    0)   // cvt x(t)  <-A, load x(t+2)->A
        STEPX(1, 0, 1, sBa, sBb, F_IN, 0)   // cvt x(t+1)<-B, load x(t+3)->B
        xp2 += 2 * F_IN;
    }
    // tail: t = 510 (cvt x(510) from A, no load), t = 511 (cvt x(511) from B,
    // LAST -> Hf)
    STEPX(0, 1, 0, sAa, sAb, 0, 0)
    STEPX(1, 0, 0, sBa, sBb, 0, 1)

    // ---------------- epilogue: out[b] = h . dense_w + dense_b --------------
    if (tid < BC) {
        float acc = dense_b[0];
        #pragma unroll 4
        for (int uu = 0; uu < H_DIM; ++uu)
            acc = fmaf(Hf[tid][uu], dense_w[uu], acc);
        out[b0 + tid] = acc;
    }
}

extern "C" void kernel_launch(void* const* d_in, const int* in_sizes, int n_in,
                              void* d_out, int out_size, void* d_ws, size_t ws_size,
                              hipStream_t stream) {
    const float* x       = (const float*)d_in[0];
    const float* wk      = (const float*)d_in[1];
    const float* bias    = (const float*)d_in[2];
    const float* dense_w = (const float*)d_in[3];
    const float* dense_b = (const float*)d_in[4];
    float* out = (float*)d_out;

    lstm_mfma_kernel<<<B_TOTAL / BC, 512, 0, stream>>>(
        x, wk, bias, dense_w, dense_b, out);
}